// Round 7
// baseline (840.389 us; speedup 1.0000x reference)
//
#include <hip/hip_runtime.h>

// ---------------------------------------------------------------------------
// VectorQuantizer, np-fp32-faithful argmin. Round 12 = round 11 + reg diet:
//   ROUND-11 POST-MORTEM: reg-scan killed bank conflicts (16.8M -> 0) but
//   WRITE 16->246MB, FETCH +200MB, VALU 41->51% => scratch spill. Cause:
//   launch_bounds(512,4) => unified cap 512/4 = 128 regs/wave; reg-scan needs
//   acc(64)+topk(32)+frags(32)+misc(~20) ~= 148 > 128.
//   DIET (target ~120 regs, keep 2 blocks/CU):
//     1) topk ids packed 2x16b/set (ids<8192): 4x(4k+2i)=24 regs (-8);
//        unpack for merge AFTER ct loop when acc is dead.
//     2) i-outer COMPUTE: af[4] preloaded, bv loaded per-i: frag peak 20 (-12)
//     3) ds_read imm offsets from abase/bbase (+i*1024) instead of aoff[]/
//        boff[] arrays (-6)
//   Semantics unchanged vs round 11 (passed, absmax 0): swapped-operand MFMA,
//   top-4 per (row, by, wn) 512-code interleaved subset, lex (key,id) merge.
//   - round-10 pipeline kept: triple-buffer 24KB, STAGE-after-barrier,
//     counted vmcnt(3) (never 0 in loop), BK=32, M-tile 256, grid 1024
// Scratch inside d_out quantized region (overwritten by writeout_k):
//   [0) zb 32MB][32M) eb 8MB][40M) b32 32KB][+32K) a32 128KB]
//   [+128K) candk 8MB][+8M) candi 8MB]   (ends ~58.9MB < 64MB)
// d_ws: 8 bytes (loss accumulator).
// ---------------------------------------------------------------------------

#define N_ROWS 32768
#define K_CODES 8192
#define DIM 512

typedef __attribute__((ext_vector_type(8))) short short8;
typedef __attribute__((ext_vector_type(4))) float f32x4;

#define MARGIN 5e-4f

__device__ __forceinline__ unsigned short f2bf(float f) {
  unsigned int u = __float_as_uint(f);
  u = u + 0x7fffu + ((u >> 16) & 1u);   // round-to-nearest-even
  return (unsigned short)(u >> 16);
}

__device__ __forceinline__ double shfl_xor_dbl(double v, int m) {
  union { double d; int i[2]; } u;
  u.d = v;
  u.i[0] = __shfl_xor(u.i[0], m, 64);
  u.i[1] = __shfl_xor(u.i[1], m, 64);
  return u.d;
}

// opaque: block fp contraction across this value (keep separate RN32 steps)
__device__ __forceinline__ float opaque_f(float x) {
  asm volatile("" : "+v"(x));
  return x;
}

// ------- 1) fused fp32 -> bf16 + row squared-norm (one wave per row) -------
__global__ __launch_bounds__(256) void cvtnorm_k(const float* __restrict__ in,
                                                 unsigned short* __restrict__ outb,
                                                 float* __restrict__ outn) {
  const int r = blockIdx.x * 4 + (threadIdx.x >> 6);
  const int lane = threadIdx.x & 63;
  const float* xr = in + (size_t)r * DIM + lane * 8;
  const float4 a = *(const float4*)xr;
  const float4 b = *(const float4*)(xr + 4);
  uint4 o;
  o.x = (unsigned)f2bf(a.x) | ((unsigned)f2bf(a.y) << 16);
  o.y = (unsigned)f2bf(a.z) | ((unsigned)f2bf(a.w) << 16);
  o.z = (unsigned)f2bf(b.x) | ((unsigned)f2bf(b.y) << 16);
  o.w = (unsigned)f2bf(b.z) | ((unsigned)f2bf(b.w) << 16);
  *(uint4*)(outb + (size_t)r * DIM + lane * 8) = o;
  double s = (double)a.x * a.x + (double)a.y * a.y + (double)a.z * a.z + (double)a.w * a.w
           + (double)b.x * b.x + (double)b.y * b.y + (double)b.z * b.z + (double)b.w * b.w;
#pragma unroll
  for (int m = 1; m < 64; m <<= 1) s += shfl_xor_dbl(s, m);
  if (lane == 0) outn[r] = (float)s;
}

// ---------------- 2) bf16 GEMM + fused in-register top-4 -------------------
// grid 1024: bx=blk>>3 -> 256 z-rows; by=blk&7 -> 1024-code chunk (ct<8).
// Block 512 = 8 waves 4x2 (wm rows x wn code-half); wave tile 64 rows x 64
// codes = 4x4 MFMA 16x16x32, SWAPPED operands: acc[i][j] i=code-block,
// j=row-block; D reg axis (quad*4+r) = code, D lane axis (lcol) = z-row.
// Triple-buffered staging (24KB each): 0 / 24576 / 49152; e2sAll at 73728.
// LDS total 77824 -> 2 blocks/CU. Swizzle: slot s of row r <- chunk s^((r>>1)&3).

// topk set J: keys tk J 0..3 (f32); ids packed tl (id0|id1<<16), th (id2|id3<<16)
#define DECL_TOPK(J) \
  float tk##J##0 = 3.4e38f, tk##J##1 = 3.4e38f, tk##J##2 = 3.4e38f, tk##J##3 = 3.4e38f; \
  unsigned tl##J = 0u, th##J = 0u;

// hot-path insert, packed ids: strict key-<; ascending-id traversal keeps
// earliest id (ids only move, never compared here — same as round 11 INS)
#define INS(J, sv, idv) do { \
    if ((sv) < tk##J##3) { \
      const unsigned v_ = (unsigned)(idv); \
      if ((sv) < tk##J##2) { \
        if ((sv) < tk##J##1) { \
          tk##J##3 = tk##J##2; tk##J##2 = tk##J##1; \
          th##J = ((th##J & 0xFFFFu) << 16) | (tl##J >> 16); \
          if ((sv) < tk##J##0) { tk##J##1 = tk##J##0; tk##J##0 = (sv); \
            tl##J = (tl##J << 16) | v_; \
          } else { tk##J##1 = (sv); \
            tl##J = (tl##J & 0xFFFFu) | (v_ << 16); \
          } \
        } else { tk##J##3 = tk##J##2; tk##J##2 = (sv); \
          th##J = ((th##J & 0xFFFFu) << 16) | v_; \
        } \
      } else { tk##J##3 = (sv); \
        th##J = (th##J & 0xFFFFu) | (v_ << 16); \
      } \
    } \
  } while (0)

#define SCAN_J(J) do { \
    float s0_ = fmaf(acc[i][J][0], -2.0f, ev4.x), s1_ = fmaf(acc[i][J][1], -2.0f, ev4.y); \
    float s2_ = fmaf(acc[i][J][2], -2.0f, ev4.z), s3_ = fmaf(acc[i][J][3], -2.0f, ev4.w); \
    const float mn_ = fminf(fminf(s0_, s1_), fminf(s2_, s3_)); \
    if (mn_ < tk##J##3) { \
      INS(J, s0_, id0); INS(J, s1_, id0 + 1); INS(J, s2_, id0 + 2); INS(J, s3_, id0 + 3); \
    } \
  } while (0)

// merge insert (unpacked ids): full lexicographic (key,id) — identical to r11
#define LTL(sv, idv, K, I) ((sv) < (K) || ((sv) == (K) && (idv) < (I)))
#define INSM(J, sv, idv) do { \
    if (LTL(sv, idv, tk##J##3, ui##J##3)) { \
      if (LTL(sv, idv, tk##J##2, ui##J##2)) { tk##J##3 = tk##J##2; ui##J##3 = ui##J##2; \
        if (LTL(sv, idv, tk##J##1, ui##J##1)) { tk##J##2 = tk##J##1; ui##J##2 = ui##J##1; \
          if (LTL(sv, idv, tk##J##0, ui##J##0)) { tk##J##1 = tk##J##0; ui##J##1 = ui##J##0; tk##J##0 = (sv); ui##J##0 = (idv); } \
          else { tk##J##1 = (sv); ui##J##1 = (idv); } \
        } else { tk##J##2 = (sv); ui##J##2 = (idv); } \
      } else { tk##J##3 = (sv); ui##J##3 = (idv); } \
    } \
  } while (0)

#define MERGE_STEP(J, M) do { \
    float ok0 = __shfl_xor(tk##J##0, M, 64), ok1 = __shfl_xor(tk##J##1, M, 64); \
    float ok2 = __shfl_xor(tk##J##2, M, 64), ok3 = __shfl_xor(tk##J##3, M, 64); \
    int oi0 = __shfl_xor(ui##J##0, M, 64), oi1 = __shfl_xor(ui##J##1, M, 64); \
    int oi2 = __shfl_xor(ui##J##2, M, 64), oi3 = __shfl_xor(ui##J##3, M, 64); \
    INSM(J, ok0, oi0); INSM(J, ok1, oi1); INSM(J, ok2, oi2); INSM(J, ok3, oi3); \
  } while (0)

#define UNPACK(J) \
  int ui##J##0 = (int)(tl##J & 0xFFFFu), ui##J##1 = (int)(tl##J >> 16); \
  int ui##J##2 = (int)(th##J & 0xFFFFu), ui##J##3 = (int)(th##J >> 16);

__global__ __launch_bounds__(512, 4) void gemm_topk(
    const unsigned short* __restrict__ A,   // z bf16 [32768][512]
    const unsigned short* __restrict__ B,   // e bf16 [8192][512]
    const float* __restrict__ en2,          // [8192] = b32
    float* __restrict__ candk,              // [32768][64]
    int* __restrict__ candi)                // [32768][64]
{
  __shared__ char lds[77824];
  float* e2sAll = (float*)(lds + 73728);         // [1024]

  const int tid = threadIdx.x;
  const int lane = tid & 63, wave = tid >> 6;    // wave 0..7
  const int wm = wave >> 1, wn = wave & 1;       // 4x2 wave grid
  const int quad = lane >> 4, lcol = lane & 15;
  const int bx = blockIdx.x >> 3, by = blockIdx.x & 7;
  const int row0 = bx * 256;
  const int cstart = by * 1024;                  // FULL coverage: 8 x 1024

  // preload all 1024 e-norms for this chunk (keeps VMEM out of vmcnt count)
  e2sAll[tid] = en2[cstart + tid];
  e2sAll[tid + 512] = en2[cstart + 512 + tid];

  DECL_TOPK(0) DECL_TOPK(1) DECL_TOPK(2) DECL_TOPK(3)

  // staging: lane l covers (row = base + (l>>2), lds-slot = l&3); the source
  // chunk is pre-permuted: sch = (l&3) ^ ((l>>3)&3)  [= slot ^ ((row>>1)&3)]
  const int schm = (lane & 3) ^ ((lane >> 3) & 3);
  const unsigned short* Ag =
      A + ((size_t)(row0 + wave * 32 + (lane >> 2))) * DIM + schm * 8;
  const int dstA = wave * 2048;                  // 2 gload_lds: 16 rows each
  const int dstB = 16384 + wave * 1024;          // 16 rows per wave

  // fragment reader bases: row byte base + swizzled chunk offset; the
  // per-block offsets fold into ds_read imm: abase + j*1024 / bbase + i*1024
  const int swz = (quad ^ ((lcol >> 1) & 3)) * 16;
  const int abase = (wm * 64 + lcol) * 64 + swz;
  const int bbase = 16384 + (wn * 64 + lcol) * 64 + swz;

#define ASGP const __attribute__((address_space(1))) void*
#define LDSP __attribute__((address_space(3))) void*
#define STAGE(ktv, bb) do {                                                        \
    const unsigned short* As_ = Ag + (ktv) * 32;                                   \
    const unsigned short* Bs_ = Bg + (ktv) * 32;                                   \
    __builtin_amdgcn_global_load_lds((ASGP)(uintptr_t)(As_),                       \
        (LDSP)(uintptr_t)(lds + (bb) + dstA), 16, 0, 0);                           \
    __builtin_amdgcn_global_load_lds((ASGP)(uintptr_t)(As_ + 16 * DIM),            \
        (LDSP)(uintptr_t)(lds + (bb) + dstA + 1024), 16, 0, 0);                    \
    __builtin_amdgcn_global_load_lds((ASGP)(uintptr_t)(Bs_),                       \
        (LDSP)(uintptr_t)(lds + (bb) + dstB), 16, 0, 0);                           \
  } while (0)

// SWAPPED operands: A-operand = code fragment (bv), B-operand = row fragment
// (af). i-outer: af[4] preloaded (16 regs), bv loaded per-i (4 regs) ->
// fragment peak 20 regs (was 32). Same 8 ds_read_b128 per kt.
#define COMPUTE(cbb) do {                                                          \
    short8 af_[4];                                                                 \
    _Pragma("unroll")                                                              \
    for (int j = 0; j < 4; ++j)                                                    \
      af_[j] = *(const short8*)(lds + (cbb) + abase + j * 1024);                   \
    _Pragma("unroll")                                                              \
    for (int i = 0; i < 4; ++i) {                                                  \
      const short8 bv_ = *(const short8*)(lds + (cbb) + bbase + i * 1024);         \
      _Pragma("unroll")                                                            \
      for (int j = 0; j < 4; ++j)                                                  \
        acc[i][j] = __builtin_amdgcn_mfma_f32_16x16x32_bf16(bv_, af_[j],           \
                                                            acc[i][j], 0, 0, 0);   \
    }                                                                              \
  } while (0)

#pragma unroll 1
  for (int ct = 0; ct < 8; ++ct) {
    const int c0 = cstart + ct * 128;
    const unsigned short* Bg =
        B + ((size_t)(c0 + wave * 16 + (lane >> 2))) * DIM + schm * 8;

    f32x4 acc[4][4];
#pragma unroll
    for (int i = 0; i < 4; ++i)
#pragma unroll
      for (int j = 0; j < 4; ++j) acc[i][j] = 0.f;

    __syncthreads();                 // staging region free (all ds_reads done)
    STAGE(0, 0);
    STAGE(1, 24576);
    int cb = 0, nb = 24576, fb = 49152;   // rotating buffer bases
#pragma unroll 1
    for (int kt = 0; kt < 15; ++kt) {
      // own STAGE(kt) landed (in-order retirement; kt+1 may stay in flight)
      asm volatile("s_waitcnt vmcnt(3)" ::: "memory");
      __builtin_amdgcn_s_barrier();          // => ALL waves' STAGE(kt) landed
      asm volatile("" ::: "memory");         // no memory op hoists above barrier
      __builtin_amdgcn_sched_barrier(0);
      // fb == buffer read at COMPUTE(kt-1); its readers retired their ds_reads
      // before the barrier above -> safe to overwrite now.
      if (kt < 14) STAGE(kt + 2, fb);
      COMPUTE(cb);
      const int t = cb; cb = nb; nb = fb; fb = t;
    }
    asm volatile("s_waitcnt vmcnt(0)" ::: "memory");
    __builtin_amdgcn_s_barrier();
    asm volatile("" ::: "memory");
    __builtin_amdgcn_sched_barrier(0);
    COMPUTE(cb);                     // kt=15 (15%3==0 -> cb cycled back to 0)

    // ---- in-register scan: 64 scores/lane, no LDS round-trip ----
#pragma unroll
    for (int i = 0; i < 4; ++i) {
      const int eb = ct * 128 + wn * 64 + i * 16 + quad * 4;
      const float4 ev4 = *(const float4*)(e2sAll + eb);
      const int id0 = cstart + eb;
      SCAN_J(0); SCAN_J(1); SCAN_J(2); SCAN_J(3);
    }
  }

  // unpack ids (acc dead now -> register headroom), then butterfly merge
  // across the 4 quad-lanes ((key,id) lexicographic -> identical union top-4)
  UNPACK(0) UNPACK(1) UNPACK(2) UNPACK(3)
  MERGE_STEP(0, 16); MERGE_STEP(1, 16); MERGE_STEP(2, 16); MERGE_STEP(3, 16);
  MERGE_STEP(0, 32); MERGE_STEP(1, 32); MERGE_STEP(2, 32); MERGE_STEP(3, 32);

  if (quad == 0) {
#define WOUT(J) do { \
      const size_t cb2 = ((size_t)(row0 + wm * 64 + (J) * 16 + lcol)) * 64 + by * 8 + wn * 4; \
      float4 kf; kf.x = tk##J##0; kf.y = tk##J##1; kf.z = tk##J##2; kf.w = tk##J##3; \
      int4 fi; fi.x = ui##J##0; fi.y = ui##J##1; fi.z = ui##J##2; fi.w = ui##J##3; \
      *(float4*)(candk + cb2) = kf; *(int4*)(candi + cb2) = fi; \
    } while (0)
    WOUT(0); WOUT(1); WOUT(2); WOUT(3);
  }
}

// ---------------- 3) np-faithful fp32 rescore, wave-per-row ----------------
// One wave per row; LANE j owns candidate j (64 in parallel). Per-candidate
// arithmetic bit-identical: OpenBLAS sgemm model m32 = RN32(chain(0..383) +
// chain(384..511)), sequential fp32 fma chains; d = RN32(RN32(a+b)-RN32(2m)).
// Winner = lexicographic min (d, c).
__global__ __launch_bounds__(256) void rescore_np(
    const float* __restrict__ z, const float* __restrict__ e,
    const float* __restrict__ a32, const float* __restrict__ b32,
    const float* __restrict__ candk, const int* __restrict__ candi,
    float* __restrict__ idxout)
{
  const int row = blockIdx.x * 4 + (threadIdx.x >> 6);
  const int lane = threadIdx.x & 63;

  const float myk = candk[(size_t)row * 64 + lane];
  float kmin = myk;
#pragma unroll
  for (int m = 1; m < 64; m <<= 1) kmin = fminf(kmin, __shfl_xor(kmin, m, 64));
  const float cut = kmin + MARGIN;

  float bd = 3.4e38f;
  int bc = 0x7fffffff;
  if (myk <= cut) {
    const int c = candi[(size_t)row * 64 + lane];
    const float* zr = z + (size_t)row * DIM;
    const float* er = e + (size_t)c * DIM;
    // panel A: k = 0..383, sequential fp32 fma chain
    float s = 0.0f;
#pragma unroll 4
    for (int k4 = 0; k4 < 96; ++k4) {
      const float4 zv = *(const float4*)(zr + k4 * 4);
      const float4 ev = *(const float4*)(er + k4 * 4);
      s = fmaf(zv.x, ev.x, s);
      s = fmaf(zv.y, ev.y, s);
      s = fmaf(zv.z, ev.z, s);
      s = fmaf(zv.w, ev.w, s);
    }
    const float cA = s;
    // panel B: k = 384..511
    s = 0.0f;
#pragma unroll 4
    for (int k4 = 96; k4 < 128; ++k4) {
      const float4 zv = *(const float4*)(zr + k4 * 4);
      const float4 ev = *(const float4*)(er + k4 * 4);
      s = fmaf(zv.x, ev.x, s);
      s = fmaf(zv.y, ev.y, s);
      s = fmaf(zv.z, ev.z, s);
      s = fmaf(zv.w, ev.w, s);
    }
    const float m = cA + s;                    // RN32 panel combine
    const float t1 = a32[row] + b32[c];        // RN32(a + b_c)
    const float t2 = opaque_f(2.0f * m);       // RN32(2*m), no contraction
    bd = t1 - t2;                              // RN32(t1 - t2)
    bc = c;
  }
  // lexicographic (d, c) min across the wave
#pragma unroll
  for (int mm = 1; mm < 64; mm <<= 1) {
    const float od = __shfl_xor(bd, mm, 64);
    const int oc = __shfl_xor(bc, mm, 64);
    if (od < bd || (od == bd && oc < bc)) { bd = od; bc = oc; }
  }
  if (lane == 0) idxout[row] = (float)bc;
}

// ---------------- 4) gather + straight-through output + loss ---------------
// Grid-stride over 4,194,304 float4-chunks with 1024 blocks: ONE fp64 atomic
// per block.
__global__ __launch_bounds__(256) void writeout_k(
    const float* __restrict__ z, const float* __restrict__ e,
    const float* __restrict__ idxf, float* __restrict__ outq,
    double* __restrict__ accum)
{
  const int tid = threadIdx.x;
  double s = 0.0;
  size_t gid = (size_t)blockIdx.x * 256 + tid;
#pragma unroll 1
  for (int it = 0; it < 16; ++it, gid += 262144) {
    const int row = (int)(gid >> 7);
    const int dq = ((int)gid & 127) << 2;
    const int c = (int)idxf[row];
    const float4 q4 = *(const float4*)(e + (size_t)c * DIM + dq);
    const float4 z4 = *(const float4*)(z + (size_t)row * DIM + dq);
    const float tx = q4.x - z4.x, ty = q4.y - z4.y, tz = q4.z - z4.z, tw = q4.w - z4.w;
    float4 o;
    o.x = z4.x + tx; o.y = z4.y + ty; o.z = z4.z + tz; o.w = z4.w + tw;
    *(float4*)(outq + (size_t)row * DIM + dq) = o;
    s += (double)tx * tx + (double)ty * ty + (double)tz * tz + (double)tw * tw;
  }
#pragma unroll
  for (int m = 1; m < 64; m <<= 1) s += shfl_xor_dbl(s, m);
  __shared__ double wsum[4];
  if ((tid & 63) == 0) wsum[tid >> 6] = s;
  __syncthreads();
  if (tid == 0) atomicAdd(accum, wsum[0] + wsum[1] + wsum[2] + wsum[3]);
}

// ---------------- 5) finalize loss -----------------------------------------
__global__ void finalize_k(const double* __restrict__ accum, float* __restrict__ lossp) {
  *lossp = (float)(1.25 * accum[0] / (double)((size_t)N_ROWS * DIM));
}

// ---------------------------------------------------------------------------
extern "C" void kernel_launch(void* const* d_in, const int* in_sizes, int n_in,
                              void* d_out, int out_size, void* d_ws, size_t ws_size,
                              hipStream_t stream) {
  const float* z = (const float*)d_in[0];   // [32768*512] f32
  const float* e = (const float*)d_in[1];   // [8192*512]  f32
  float* out = (float*)d_out;
  char* ob = (char*)d_out;

  // scratch inside the 64MB quantized region (overwritten by writeout_k)
  unsigned short* zb = (unsigned short*)ob;                  // 33,554,432 B
  unsigned short* eb = (unsigned short*)(ob + 33554432);     //  8,388,608 B
  float* b32   = (float*)(ob + 41943040);                    //     32,768 B
  float* a32   = (float*)(ob + 41975808);                    //    131,072 B
  float* candk = (float*)(ob + 42106880);                    //  8,388,608 B
  int*   candi = (int*)(ob + 50495488);                      //  8,388,608 B

  float* lossp = out + 16777216;
  float* idxs  = out + 16777217;
  double* accum = (double*)d_ws;

  hipMemsetAsync(d_ws, 0, sizeof(double), stream);
  cvtnorm_k<<<8192, 256, 0, stream>>>(z, zb, a32);
  cvtnorm_k<<<2048, 256, 0, stream>>>(e, eb, b32);
  gemm_topk<<<1024, 512, 0, stream>>>(zb, eb, b32, candk, candi);
  rescore_np<<<8192, 256, 0, stream>>>(z, e, a32, b32, candk, candi, idxs);
  writeout_k<<<1024, 256, 0, stream>>>(z, e, idxs, out, accum);
  finalize_k<<<1, 1, 0, stream>>>(accum, lossp);
}

// Round 8
// 799.705 us; speedup vs baseline: 1.0509x; 1.0509x over previous
//
#include <hip/hip_runtime.h>

// ---------------------------------------------------------------------------
// VectorQuantizer, np-fp32-faithful argmin. Round 13 = r10 revert + trims:
//   A/B VERDICT r10 vs r11/r12: reg-scan removed all bank conflicts but lost
//   anyway (449 vs 423): gemm is bubble-bound (LDS ~55%, VALU ~50%, MFMA 27%,
//   no pipe saturated) -> shaving a non-critical pipe doesn't move the wall.
//   REVERT gemm to r10 exactly (423us, absmax 0), plus ONE surgical delta:
//   s_setprio(1) around the MFMA cluster (T5; 2 async blocks/CU = role split
//   for the CU scheduler; worst case -1.5% per m190).
//   NEW: fused cvtnorm (z+e in one launch, wave-uniform branch) — non-gemm
//   time is ~365us flat across rounds vs ~150us modeled work; cutting a
//   launch tests the fixed-overhead theory cheaply.
//   - r10 pipeline: triple-buffer 24KB, STAGE-after-barrier, counted
//     vmcnt(3) (never 0 in loop), BK=32, M-tile 256, grid 1024, scorebuf
//     [256][67] aliasing staging, swizzle slot s <- chunk s^((r>>1)&3)
// Scratch inside d_out quantized region (overwritten by writeout_k):
//   [0) zb 32MB][32M) eb 8MB][40M) b32 32KB][+32K) a32 128KB]
//   [+128K) candk 8MB][+8M) candi 8MB]   (ends ~58.9MB < 64MB)
// d_ws: 8 bytes (loss accumulator).
// ---------------------------------------------------------------------------

#define N_ROWS 32768
#define K_CODES 8192
#define DIM 512

typedef __attribute__((ext_vector_type(8))) short short8;
typedef __attribute__((ext_vector_type(4))) float f32x4;

#define MARGIN 5e-4f

__device__ __forceinline__ unsigned short f2bf(float f) {
  unsigned int u = __float_as_uint(f);
  u = u + 0x7fffu + ((u >> 16) & 1u);   // round-to-nearest-even
  return (unsigned short)(u >> 16);
}

__device__ __forceinline__ double shfl_xor_dbl(double v, int m) {
  union { double d; int i[2]; } u;
  u.d = v;
  u.i[0] = __shfl_xor(u.i[0], m, 64);
  u.i[1] = __shfl_xor(u.i[1], m, 64);
  return u.d;
}

// opaque: block fp contraction across this value (keep separate RN32 steps)
__device__ __forceinline__ float opaque_f(float x) {
  asm volatile("" : "+v"(x));
  return x;
}

// --- 1) fused fp32 -> bf16 + row squared-norm, z AND e in one launch -------
// grid 10240: blocks 0..8191 -> z rows, 8192..10239 -> e rows. Per-wave
// uniform branch (4 rows/block, wave-per-row).
__global__ __launch_bounds__(256) void cvtnorm_k(
    const float* __restrict__ z, const float* __restrict__ e,
    unsigned short* __restrict__ zb, unsigned short* __restrict__ eb,
    float* __restrict__ a32, float* __restrict__ b32) {
  const int r = blockIdx.x * 4 + (threadIdx.x >> 6);
  const int lane = threadIdx.x & 63;
  const float* in; unsigned short* outb; float* outn; int rr;
  if (r < N_ROWS) { in = z; outb = zb; outn = a32; rr = r; }
  else            { in = e; outb = eb; outn = b32; rr = r - N_ROWS; }
  const float* xr = in + (size_t)rr * DIM + lane * 8;
  const float4 a = *(const float4*)xr;
  const float4 b = *(const float4*)(xr + 4);
  uint4 o;
  o.x = (unsigned)f2bf(a.x) | ((unsigned)f2bf(a.y) << 16);
  o.y = (unsigned)f2bf(a.z) | ((unsigned)f2bf(a.w) << 16);
  o.z = (unsigned)f2bf(b.x) | ((unsigned)f2bf(b.y) << 16);
  o.w = (unsigned)f2bf(b.z) | ((unsigned)f2bf(b.w) << 16);
  *(uint4*)(outb + (size_t)rr * DIM + lane * 8) = o;
  double s = (double)a.x * a.x + (double)a.y * a.y + (double)a.z * a.z + (double)a.w * a.w
           + (double)b.x * b.x + (double)b.y * b.y + (double)b.z * b.z + (double)b.w * b.w;
#pragma unroll
  for (int m = 1; m < 64; m <<= 1) s += shfl_xor_dbl(s, m);
  if (lane == 0) outn[rr] = (float)s;
}

// ---------------- 2) bf16 GEMM + fused streamed top-4 ----------------------
// EXACT round-10 structure (423us, absmax 0) + T5 setprio around MFMA.
// grid 1024: bx=blk>>3 -> 256 z-rows; by=blk&7 -> 1024-code chunk (ct<8).
// Block 512 = 8 waves 4x2; wave tile 64x64 = 4x4 MFMA 16x16x32; BK=32.
// Triple-buffered staging (24KB each): 0 / 24576 / 49152.
// scorebuf [256][67] f32 aliases [0,68608) (used only after drained kt loop);
// e2sAll [1024] f32 at 73728. LDS total 77824 -> 2 blocks/CU.
// Swizzle: row r (64B) slot s holds source chunk s ^ ((r>>1)&3).
__global__ __launch_bounds__(512, 4) void gemm_topk(
    const unsigned short* __restrict__ A,   // z bf16 [32768][512]
    const unsigned short* __restrict__ B,   // e bf16 [8192][512]
    const float* __restrict__ en2,          // [8192] = b32
    float* __restrict__ candk,              // [32768][64]
    int* __restrict__ candi)                // [32768][64]
{
  __shared__ char lds[77824];
  float* scorebuf = (float*)lds;                 // [256][67], aliases staging
  float* e2sAll = (float*)(lds + 73728);         // [1024]

  const int tid = threadIdx.x;
  const int lane = tid & 63, wave = tid >> 6;    // wave 0..7
  const int wm = wave >> 1, wn = wave & 1;       // 4x2 wave grid
  const int quad = lane >> 4, lcol = lane & 15;
  const int bx = blockIdx.x >> 3, by = blockIdx.x & 7;
  const int row0 = bx * 256;
  const int cstart = by * 1024;                  // FULL coverage: 8 x 1024
  const int hf = tid & 1, srow = tid >> 1;       // scan ownership (srow 0..255)

  // preload all 1024 e-norms for this chunk (keeps VMEM out of vmcnt count)
  e2sAll[tid] = en2[cstart + tid];
  e2sAll[tid + 512] = en2[cstart + 512 + tid];

  float tk0 = 3.4e38f, tk1 = 3.4e38f, tk2 = 3.4e38f, tk3 = 3.4e38f;
  int ti0 = 0, ti1 = 0, ti2 = 0, ti3 = 0;

  // staging: lane l covers (row = base + (l>>2), lds-slot = l&3); the source
  // chunk is pre-permuted: sch = (l&3) ^ ((l>>3)&3)  [= slot ^ ((row>>1)&3)]
  const int schm = (lane & 3) ^ ((lane >> 3) & 3);
  const unsigned short* Ag =
      A + ((size_t)(row0 + wave * 32 + (lane >> 2))) * DIM + schm * 8;
  const int dstA = wave * 2048;                  // 2 gload_lds: 16 rows each
  const int dstB = 16384 + wave * 1024;          // 16 rows per wave

  // fragment readers: row byte base + swizzled chunk offset
  const int swz = (quad ^ ((lcol >> 1) & 3)) * 16;
  int aoff[4], boff[4];
#pragma unroll
  for (int i = 0; i < 4; ++i) aoff[i] = (wm * 64 + i * 16 + lcol) * 64 + swz;
#pragma unroll
  for (int j = 0; j < 4; ++j) boff[j] = 16384 + (wn * 64 + j * 16 + lcol) * 64 + swz;

#define ASGP const __attribute__((address_space(1))) void*
#define LDSP __attribute__((address_space(3))) void*
#define STAGE(ktv, bb) do {                                                        \
    const unsigned short* As_ = Ag + (ktv) * 32;                                   \
    const unsigned short* Bs_ = Bg + (ktv) * 32;                                   \
    __builtin_amdgcn_global_load_lds((ASGP)(uintptr_t)(As_),                       \
        (LDSP)(uintptr_t)(lds + (bb) + dstA), 16, 0, 0);                           \
    __builtin_amdgcn_global_load_lds((ASGP)(uintptr_t)(As_ + 16 * DIM),            \
        (LDSP)(uintptr_t)(lds + (bb) + dstA + 1024), 16, 0, 0);                    \
    __builtin_amdgcn_global_load_lds((ASGP)(uintptr_t)(Bs_),                       \
        (LDSP)(uintptr_t)(lds + (bb) + dstB), 16, 0, 0);                           \
  } while (0)

#define COMPUTE(cbb) do {                                                          \
    short8 af[4], bv[4];                                                           \
    _Pragma("unroll")                                                              \
    for (int i = 0; i < 4; ++i) af[i] = *(const short8*)(lds + (cbb) + aoff[i]);   \
    _Pragma("unroll")                                                              \
    for (int j = 0; j < 4; ++j) bv[j] = *(const short8*)(lds + (cbb) + boff[j]);   \
    __builtin_amdgcn_s_setprio(1);                                                 \
    _Pragma("unroll")                                                              \
    for (int i = 0; i < 4; ++i)                                                    \
      _Pragma("unroll")                                                            \
      for (int j = 0; j < 4; ++j)                                                  \
        acc[i][j] = __builtin_amdgcn_mfma_f32_16x16x32_bf16(af[i], bv[j],          \
                                                            acc[i][j], 0, 0, 0);   \
    __builtin_amdgcn_s_setprio(0);                                                 \
  } while (0)

#pragma unroll 1
  for (int ct = 0; ct < 8; ++ct) {
    const int c0 = cstart + ct * 128;
    const unsigned short* Bg =
        B + ((size_t)(c0 + wave * 16 + (lane >> 2))) * DIM + schm * 8;

    f32x4 acc[4][4];
#pragma unroll
    for (int i = 0; i < 4; ++i)
#pragma unroll
      for (int j = 0; j < 4; ++j) acc[i][j] = 0.f;

    __syncthreads();                 // staging/scorebuf region free (drains all)
    STAGE(0, 0);
    STAGE(1, 24576);
    int cb = 0, nb = 24576, fb = 49152;   // rotating buffer bases
#pragma unroll 1
    for (int kt = 0; kt < 15; ++kt) {
      // own STAGE(kt) landed (in-order retirement; kt+1 may stay in flight)
      asm volatile("s_waitcnt vmcnt(3)" ::: "memory");
      __builtin_amdgcn_s_barrier();          // => ALL waves' STAGE(kt) landed
      asm volatile("" ::: "memory");         // no memory op hoists above barrier
      __builtin_amdgcn_sched_barrier(0);
      // fb == buffer read at COMPUTE(kt-1); its readers retired their ds_reads
      // before the barrier above -> safe to overwrite now.
      if (kt < 14) STAGE(kt + 2, fb);
      COMPUTE(cb);
      const int t = cb; cb = nb; nb = fb; fb = t;
    }
    asm volatile("s_waitcnt vmcnt(0)" ::: "memory");
    __builtin_amdgcn_s_barrier();
    asm volatile("" ::: "memory");
    __builtin_amdgcn_sched_barrier(0);
    COMPUTE(cb);                     // kt=15 (15%3==0 -> cb cycled back to 0)

#pragma unroll 1
    for (int h = 0; h < 2; ++h) {
      __syncthreads();
      if (wn == h) {
#pragma unroll
        for (int i = 0; i < 4; ++i)
#pragma unroll
          for (int j = 0; j < 4; ++j) {
            const float eb2 = e2sAll[ct * 128 + 64 * h + 16 * j + lcol];
#pragma unroll
            for (int r = 0; r < 4; ++r)
              scorebuf[(wm * 64 + i * 16 + quad * 4 + r) * 67 + 16 * j + lcol] =
                  fmaf(acc[i][j][r], -2.0f, eb2);
          }
      }
      __syncthreads();
      const float* sp = scorebuf + srow * 67 + hf * 32;
      const int idbase = c0 + 64 * h + 32 * hf;
#pragma unroll 8
      for (int cc = 0; cc < 32; ++cc) {
        const float key = sp[cc];
        if (key < tk3) {
          const int id = idbase + cc;
          if (key < tk2) {
            tk3 = tk2; ti3 = ti2;
            if (key < tk1) {
              tk2 = tk1; ti2 = ti1;
              if (key < tk0) { tk1 = tk0; ti1 = ti0; tk0 = key; ti0 = id; }
              else           { tk1 = key; ti1 = id; }
            } else { tk2 = key; ti2 = id; }
          } else { tk3 = key; ti3 = id; }
        }
      }
    }
  }

  const size_t cb2 = ((size_t)(row0 + srow)) * 64 + by * 8 + hf * 4;
  candk[cb2 + 0] = tk0; candk[cb2 + 1] = tk1; candk[cb2 + 2] = tk2; candk[cb2 + 3] = tk3;
  candi[cb2 + 0] = ti0; candi[cb2 + 1] = ti1; candi[cb2 + 2] = ti2; candi[cb2 + 3] = ti3;
}

// ---------------- 3) np-faithful fp32 rescore, wave-per-row ----------------
// One wave per row; LANE j owns candidate j (64 in parallel). Per-candidate
// arithmetic bit-identical: OpenBLAS sgemm model m32 = RN32(chain(0..383) +
// chain(384..511)), sequential fp32 fma chains; d = RN32(RN32(a+b)-RN32(2m)).
// Winner = lexicographic min (d, c).
__global__ __launch_bounds__(256) void rescore_np(
    const float* __restrict__ z, const float* __restrict__ e,
    const float* __restrict__ a32, const float* __restrict__ b32,
    const float* __restrict__ candk, const int* __restrict__ candi,
    float* __restrict__ idxout)
{
  const int row = blockIdx.x * 4 + (threadIdx.x >> 6);
  const int lane = threadIdx.x & 63;

  const float myk = candk[(size_t)row * 64 + lane];
  float kmin = myk;
#pragma unroll
  for (int m = 1; m < 64; m <<= 1) kmin = fminf(kmin, __shfl_xor(kmin, m, 64));
  const float cut = kmin + MARGIN;

  float bd = 3.4e38f;
  int bc = 0x7fffffff;
  if (myk <= cut) {
    const int c = candi[(size_t)row * 64 + lane];
    const float* zr = z + (size_t)row * DIM;
    const float* er = e + (size_t)c * DIM;
    // panel A: k = 0..383, sequential fp32 fma chain
    float s = 0.0f;
#pragma unroll 4
    for (int k4 = 0; k4 < 96; ++k4) {
      const float4 zv = *(const float4*)(zr + k4 * 4);
      const float4 ev = *(const float4*)(er + k4 * 4);
      s = fmaf(zv.x, ev.x, s);
      s = fmaf(zv.y, ev.y, s);
      s = fmaf(zv.z, ev.z, s);
      s = fmaf(zv.w, ev.w, s);
    }
    const float cA = s;
    // panel B: k = 384..511
    s = 0.0f;
#pragma unroll 4
    for (int k4 = 96; k4 < 128; ++k4) {
      const float4 zv = *(const float4*)(zr + k4 * 4);
      const float4 ev = *(const float4*)(er + k4 * 4);
      s = fmaf(zv.x, ev.x, s);
      s = fmaf(zv.y, ev.y, s);
      s = fmaf(zv.z, ev.z, s);
      s = fmaf(zv.w, ev.w, s);
    }
    const float m = cA + s;                    // RN32 panel combine
    const float t1 = a32[row] + b32[c];        // RN32(a + b_c)
    const float t2 = opaque_f(2.0f * m);       // RN32(2*m), no contraction
    bd = t1 - t2;                              // RN32(t1 - t2)
    bc = c;
  }
  // lexicographic (d, c) min across the wave
#pragma unroll
  for (int mm = 1; mm < 64; mm <<= 1) {
    const float od = __shfl_xor(bd, mm, 64);
    const int oc = __shfl_xor(bc, mm, 64);
    if (od < bd || (od == bd && oc < bc)) { bd = od; bc = oc; }
  }
  if (lane == 0) idxout[row] = (float)bc;
}

// ---------------- 4) gather + straight-through output + loss ---------------
// Grid-stride over 4,194,304 float4-chunks with 1024 blocks: ONE fp64 atomic
// per block.
__global__ __launch_bounds__(256) void writeout_k(
    const float* __restrict__ z, const float* __restrict__ e,
    const float* __restrict__ idxf, float* __restrict__ outq,
    double* __restrict__ accum)
{
  const int tid = threadIdx.x;
  double s = 0.0;
  size_t gid = (size_t)blockIdx.x * 256 + tid;
#pragma unroll 1
  for (int it = 0; it < 16; ++it, gid += 262144) {
    const int row = (int)(gid >> 7);
    const int dq = ((int)gid & 127) << 2;
    const int c = (int)idxf[row];
    const float4 q4 = *(const float4*)(e + (size_t)c * DIM + dq);
    const float4 z4 = *(const float4*)(z + (size_t)row * DIM + dq);
    const float tx = q4.x - z4.x, ty = q4.y - z4.y, tz = q4.z - z4.z, tw = q4.w - z4.w;
    float4 o;
    o.x = z4.x + tx; o.y = z4.y + ty; o.z = z4.z + tz; o.w = z4.w + tw;
    *(float4*)(outq + (size_t)row * DIM + dq) = o;
    s += (double)tx * tx + (double)ty * ty + (double)tz * tz + (double)tw * tw;
  }
#pragma unroll
  for (int m = 1; m < 64; m <<= 1) s += shfl_xor_dbl(s, m);
  __shared__ double wsum[4];
  if ((tid & 63) == 0) wsum[tid >> 6] = s;
  __syncthreads();
  if (tid == 0) atomicAdd(accum, wsum[0] + wsum[1] + wsum[2] + wsum[3]);
}

// ---------------- 5) finalize loss -----------------------------------------
__global__ void finalize_k(const double* __restrict__ accum, float* __restrict__ lossp) {
  *lossp = (float)(1.25 * accum[0] / (double)((size_t)N_ROWS * DIM));
}

// ---------------------------------------------------------------------------
extern "C" void kernel_launch(void* const* d_in, const int* in_sizes, int n_in,
                              void* d_out, int out_size, void* d_ws, size_t ws_size,
                              hipStream_t stream) {
  const float* z = (const float*)d_in[0];   // [32768*512] f32
  const float* e = (const float*)d_in[1];   // [8192*512]  f32
  float* out = (float*)d_out;
  char* ob = (char*)d_out;

  // scratch inside the 64MB quantized region (overwritten by writeout_k)
  unsigned short* zb = (unsigned short*)ob;                  // 33,554,432 B
  unsigned short* eb = (unsigned short*)(ob + 33554432);     //  8,388,608 B
  float* b32   = (float*)(ob + 41943040);                    //     32,768 B
  float* a32   = (float*)(ob + 41975808);                    //    131,072 B
  float* candk = (float*)(ob + 42106880);                    //  8,388,608 B
  int*   candi = (int*)(ob + 50495488);                      //  8,388,608 B

  float* lossp = out + 16777216;
  float* idxs  = out + 16777217;
  double* accum = (double*)d_ws;

  hipMemsetAsync(d_ws, 0, sizeof(double), stream);
  cvtnorm_k<<<10240, 256, 0, stream>>>(z, e, zb, eb, a32, b32);
  gemm_topk<<<1024, 512, 0, stream>>>(zb, eb, b32, candk, candi);
  rescore_np<<<8192, 256, 0, stream>>>(z, e, a32, b32, candk, candi, idxs);
  writeout_k<<<1024, 256, 0, stream>>>(z, e, idxs, out, accum);
  finalize_k<<<1, 1, 0, stream>>>(accum, lossp);
}

// Round 9
// 784.908 us; speedup vs baseline: 1.0707x; 1.0189x over previous
//
#include <hip/hip_runtime.h>

// ---------------------------------------------------------------------------
// VectorQuantizer, np-fp32-faithful argmin. Round 14 = r10 gemm (exact) +
// fused cvtnorm:
//   A/B LEDGER: r10 gemm 423us (best). r11 reg-scan 449 (spill). r12 diet
//   449 (VALU). r13 = r10+setprio 438 (T5 needs 8-phase regime; our coarse
//   2-phase-per-kt is m190's null/negative case) + FETCH/WRITE perturbation.
//   => REVERT setprio; gemm is verbatim r10. Keep r13's fused cvtnorm
//   (one launch, neutral-to-positive: non-gemm 362 vs 365us).
//   - gemm: triple-buffer 24KB (0/24576/49152), STAGE-after-barrier,
//     counted vmcnt(3) (never 0 in loop), BK=32, M-tile 256, grid 1024,
//     scorebuf [256][67] aliasing staging, swizzle slot s <- chunk s^((r>>1)&3)
//   - wave-per-row lane-per-candidate rescore, grid-stride writeout (1024
//     atomics), finalize
// Scratch inside d_out quantized region (overwritten by writeout_k):
//   [0) zb 32MB][32M) eb 8MB][40M) b32 32KB][+32K) a32 128KB]
//   [+128K) candk 8MB][+8M) candi 8MB]   (ends ~58.9MB < 64MB)
// d_ws: 8 bytes (loss accumulator).
// ---------------------------------------------------------------------------

#define N_ROWS 32768
#define K_CODES 8192
#define DIM 512

typedef __attribute__((ext_vector_type(8))) short short8;
typedef __attribute__((ext_vector_type(4))) float f32x4;

#define MARGIN 5e-4f

__device__ __forceinline__ unsigned short f2bf(float f) {
  unsigned int u = __float_as_uint(f);
  u = u + 0x7fffu + ((u >> 16) & 1u);   // round-to-nearest-even
  return (unsigned short)(u >> 16);
}

__device__ __forceinline__ double shfl_xor_dbl(double v, int m) {
  union { double d; int i[2]; } u;
  u.d = v;
  u.i[0] = __shfl_xor(u.i[0], m, 64);
  u.i[1] = __shfl_xor(u.i[1], m, 64);
  return u.d;
}

// opaque: block fp contraction across this value (keep separate RN32 steps)
__device__ __forceinline__ float opaque_f(float x) {
  asm volatile("" : "+v"(x));
  return x;
}

// --- 1) fused fp32 -> bf16 + row squared-norm, z AND e in one launch -------
// grid 10240: blocks 0..8191 -> z rows, 8192..10239 -> e rows. Per-wave
// uniform branch (4 rows/block, wave-per-row).
__global__ __launch_bounds__(256) void cvtnorm_k(
    const float* __restrict__ z, const float* __restrict__ e,
    unsigned short* __restrict__ zb, unsigned short* __restrict__ eb,
    float* __restrict__ a32, float* __restrict__ b32) {
  const int r = blockIdx.x * 4 + (threadIdx.x >> 6);
  const int lane = threadIdx.x & 63;
  const float* in; unsigned short* outb; float* outn; int rr;
  if (r < N_ROWS) { in = z; outb = zb; outn = a32; rr = r; }
  else            { in = e; outb = eb; outn = b32; rr = r - N_ROWS; }
  const float* xr = in + (size_t)rr * DIM + lane * 8;
  const float4 a = *(const float4*)xr;
  const float4 b = *(const float4*)(xr + 4);
  uint4 o;
  o.x = (unsigned)f2bf(a.x) | ((unsigned)f2bf(a.y) << 16);
  o.y = (unsigned)f2bf(a.z) | ((unsigned)f2bf(a.w) << 16);
  o.z = (unsigned)f2bf(b.x) | ((unsigned)f2bf(b.y) << 16);
  o.w = (unsigned)f2bf(b.z) | ((unsigned)f2bf(b.w) << 16);
  *(uint4*)(outb + (size_t)rr * DIM + lane * 8) = o;
  double s = (double)a.x * a.x + (double)a.y * a.y + (double)a.z * a.z + (double)a.w * a.w
           + (double)b.x * b.x + (double)b.y * b.y + (double)b.z * b.z + (double)b.w * b.w;
#pragma unroll
  for (int m = 1; m < 64; m <<= 1) s += shfl_xor_dbl(s, m);
  if (lane == 0) outn[rr] = (float)s;
}

// ---------------- 2) bf16 GEMM + fused streamed top-4 ----------------------
// EXACT round-10 structure (423us, absmax 0). No setprio.
// grid 1024: bx=blk>>3 -> 256 z-rows; by=blk&7 -> 1024-code chunk (ct<8).
// Block 512 = 8 waves 4x2; wave tile 64x64 = 4x4 MFMA 16x16x32; BK=32.
// Triple-buffered staging (24KB each): 0 / 24576 / 49152.
// scorebuf [256][67] f32 aliases [0,68608) (used only after drained kt loop);
// e2sAll [1024] f32 at 73728. LDS total 77824 -> 2 blocks/CU.
// Swizzle: row r (64B) slot s holds source chunk s ^ ((r>>1)&3).
__global__ __launch_bounds__(512, 4) void gemm_topk(
    const unsigned short* __restrict__ A,   // z bf16 [32768][512]
    const unsigned short* __restrict__ B,   // e bf16 [8192][512]
    const float* __restrict__ en2,          // [8192] = b32
    float* __restrict__ candk,              // [32768][64]
    int* __restrict__ candi)                // [32768][64]
{
  __shared__ char lds[77824];
  float* scorebuf = (float*)lds;                 // [256][67], aliases staging
  float* e2sAll = (float*)(lds + 73728);         // [1024]

  const int tid = threadIdx.x;
  const int lane = tid & 63, wave = tid >> 6;    // wave 0..7
  const int wm = wave >> 1, wn = wave & 1;       // 4x2 wave grid
  const int quad = lane >> 4, lcol = lane & 15;
  const int bx = blockIdx.x >> 3, by = blockIdx.x & 7;
  const int row0 = bx * 256;
  const int cstart = by * 1024;                  // FULL coverage: 8 x 1024
  const int hf = tid & 1, srow = tid >> 1;       // scan ownership (srow 0..255)

  // preload all 1024 e-norms for this chunk (keeps VMEM out of vmcnt count)
  e2sAll[tid] = en2[cstart + tid];
  e2sAll[tid + 512] = en2[cstart + 512 + tid];

  float tk0 = 3.4e38f, tk1 = 3.4e38f, tk2 = 3.4e38f, tk3 = 3.4e38f;
  int ti0 = 0, ti1 = 0, ti2 = 0, ti3 = 0;

  // staging: lane l covers (row = base + (l>>2), lds-slot = l&3); the source
  // chunk is pre-permuted: sch = (l&3) ^ ((l>>3)&3)  [= slot ^ ((row>>1)&3)]
  const int schm = (lane & 3) ^ ((lane >> 3) & 3);
  const unsigned short* Ag =
      A + ((size_t)(row0 + wave * 32 + (lane >> 2))) * DIM + schm * 8;
  const int dstA = wave * 2048;                  // 2 gload_lds: 16 rows each
  const int dstB = 16384 + wave * 1024;          // 16 rows per wave

  // fragment readers: row byte base + swizzled chunk offset
  const int swz = (quad ^ ((lcol >> 1) & 3)) * 16;
  int aoff[4], boff[4];
#pragma unroll
  for (int i = 0; i < 4; ++i) aoff[i] = (wm * 64 + i * 16 + lcol) * 64 + swz;
#pragma unroll
  for (int j = 0; j < 4; ++j) boff[j] = 16384 + (wn * 64 + j * 16 + lcol) * 64 + swz;

#define ASGP const __attribute__((address_space(1))) void*
#define LDSP __attribute__((address_space(3))) void*
#define STAGE(ktv, bb) do {                                                        \
    const unsigned short* As_ = Ag + (ktv) * 32;                                   \
    const unsigned short* Bs_ = Bg + (ktv) * 32;                                   \
    __builtin_amdgcn_global_load_lds((ASGP)(uintptr_t)(As_),                       \
        (LDSP)(uintptr_t)(lds + (bb) + dstA), 16, 0, 0);                           \
    __builtin_amdgcn_global_load_lds((ASGP)(uintptr_t)(As_ + 16 * DIM),            \
        (LDSP)(uintptr_t)(lds + (bb) + dstA + 1024), 16, 0, 0);                    \
    __builtin_amdgcn_global_load_lds((ASGP)(uintptr_t)(Bs_),                       \
        (LDSP)(uintptr_t)(lds + (bb) + dstB), 16, 0, 0);                           \
  } while (0)

#define COMPUTE(cbb) do {                                                          \
    short8 af[4], bv[4];                                                           \
    _Pragma("unroll")                                                              \
    for (int i = 0; i < 4; ++i) af[i] = *(const short8*)(lds + (cbb) + aoff[i]);   \
    _Pragma("unroll")                                                              \
    for (int j = 0; j < 4; ++j) bv[j] = *(const short8*)(lds + (cbb) + boff[j]);   \
    _Pragma("unroll")                                                              \
    for (int i = 0; i < 4; ++i)                                                    \
      _Pragma("unroll")                                                            \
      for (int j = 0; j < 4; ++j)                                                  \
        acc[i][j] = __builtin_amdgcn_mfma_f32_16x16x32_bf16(af[i], bv[j],          \
                                                            acc[i][j], 0, 0, 0);   \
  } while (0)

#pragma unroll 1
  for (int ct = 0; ct < 8; ++ct) {
    const int c0 = cstart + ct * 128;
    const unsigned short* Bg =
        B + ((size_t)(c0 + wave * 16 + (lane >> 2))) * DIM + schm * 8;

    f32x4 acc[4][4];
#pragma unroll
    for (int i = 0; i < 4; ++i)
#pragma unroll
      for (int j = 0; j < 4; ++j) acc[i][j] = 0.f;

    __syncthreads();                 // staging/scorebuf region free (drains all)
    STAGE(0, 0);
    STAGE(1, 24576);
    int cb = 0, nb = 24576, fb = 49152;   // rotating buffer bases
#pragma unroll 1
    for (int kt = 0; kt < 15; ++kt) {
      // own STAGE(kt) landed (in-order retirement; kt+1 may stay in flight)
      asm volatile("s_waitcnt vmcnt(3)" ::: "memory");
      __builtin_amdgcn_s_barrier();          // => ALL waves' STAGE(kt) landed
      asm volatile("" ::: "memory");         // no memory op hoists above barrier
      __builtin_amdgcn_sched_barrier(0);
      // fb == buffer read at COMPUTE(kt-1); its readers retired their ds_reads
      // before the barrier above -> safe to overwrite now.
      if (kt < 14) STAGE(kt + 2, fb);
      COMPUTE(cb);
      const int t = cb; cb = nb; nb = fb; fb = t;
    }
    asm volatile("s_waitcnt vmcnt(0)" ::: "memory");
    __builtin_amdgcn_s_barrier();
    asm volatile("" ::: "memory");
    __builtin_amdgcn_sched_barrier(0);
    COMPUTE(cb);                     // kt=15 (15%3==0 -> cb cycled back to 0)

#pragma unroll 1
    for (int h = 0; h < 2; ++h) {
      __syncthreads();
      if (wn == h) {
#pragma unroll
        for (int i = 0; i < 4; ++i)
#pragma unroll
          for (int j = 0; j < 4; ++j) {
            const float eb2 = e2sAll[ct * 128 + 64 * h + 16 * j + lcol];
#pragma unroll
            for (int r = 0; r < 4; ++r)
              scorebuf[(wm * 64 + i * 16 + quad * 4 + r) * 67 + 16 * j + lcol] =
                  fmaf(acc[i][j][r], -2.0f, eb2);
          }
      }
      __syncthreads();
      const float* sp = scorebuf + srow * 67 + hf * 32;
      const int idbase = c0 + 64 * h + 32 * hf;
#pragma unroll 8
      for (int cc = 0; cc < 32; ++cc) {
        const float key = sp[cc];
        if (key < tk3) {
          const int id = idbase + cc;
          if (key < tk2) {
            tk3 = tk2; ti3 = ti2;
            if (key < tk1) {
              tk2 = tk1; ti2 = ti1;
              if (key < tk0) { tk1 = tk0; ti1 = ti0; tk0 = key; ti0 = id; }
              else           { tk1 = key; ti1 = id; }
            } else { tk2 = key; ti2 = id; }
          } else { tk3 = key; ti3 = id; }
        }
      }
    }
  }

  const size_t cb2 = ((size_t)(row0 + srow)) * 64 + by * 8 + hf * 4;
  candk[cb2 + 0] = tk0; candk[cb2 + 1] = tk1; candk[cb2 + 2] = tk2; candk[cb2 + 3] = tk3;
  candi[cb2 + 0] = ti0; candi[cb2 + 1] = ti1; candi[cb2 + 2] = ti2; candi[cb2 + 3] = ti3;
}

// ---------------- 3) np-faithful fp32 rescore, wave-per-row ----------------
// One wave per row; LANE j owns candidate j (64 in parallel). Per-candidate
// arithmetic bit-identical: OpenBLAS sgemm model m32 = RN32(chain(0..383) +
// chain(384..511)), sequential fp32 fma chains; d = RN32(RN32(a+b)-RN32(2m)).
// Winner = lexicographic min (d, c).
__global__ __launch_bounds__(256) void rescore_np(
    const float* __restrict__ z, const float* __restrict__ e,
    const float* __restrict__ a32, const float* __restrict__ b32,
    const float* __restrict__ candk, const int* __restrict__ candi,
    float* __restrict__ idxout)
{
  const int row = blockIdx.x * 4 + (threadIdx.x >> 6);
  const int lane = threadIdx.x & 63;

  const float myk = candk[(size_t)row * 64 + lane];
  float kmin = myk;
#pragma unroll
  for (int m = 1; m < 64; m <<= 1) kmin = fminf(kmin, __shfl_xor(kmin, m, 64));
  const float cut = kmin + MARGIN;

  float bd = 3.4e38f;
  int bc = 0x7fffffff;
  if (myk <= cut) {
    const int c = candi[(size_t)row * 64 + lane];
    const float* zr = z + (size_t)row * DIM;
    const float* er = e + (size_t)c * DIM;
    // panel A: k = 0..383, sequential fp32 fma chain
    float s = 0.0f;
#pragma unroll 4
    for (int k4 = 0; k4 < 96; ++k4) {
      const float4 zv = *(const float4*)(zr + k4 * 4);
      const float4 ev = *(const float4*)(er + k4 * 4);
      s = fmaf(zv.x, ev.x, s);
      s = fmaf(zv.y, ev.y, s);
      s = fmaf(zv.z, ev.z, s);
      s = fmaf(zv.w, ev.w, s);
    }
    const float cA = s;
    // panel B: k = 384..511
    s = 0.0f;
#pragma unroll 4
    for (int k4 = 96; k4 < 128; ++k4) {
      const float4 zv = *(const float4*)(zr + k4 * 4);
      const float4 ev = *(const float4*)(er + k4 * 4);
      s = fmaf(zv.x, ev.x, s);
      s = fmaf(zv.y, ev.y, s);
      s = fmaf(zv.z, ev.z, s);
      s = fmaf(zv.w, ev.w, s);
    }
    const float m = cA + s;                    // RN32 panel combine
    const float t1 = a32[row] + b32[c];        // RN32(a + b_c)
    const float t2 = opaque_f(2.0f * m);       // RN32(2*m), no contraction
    bd = t1 - t2;                              // RN32(t1 - t2)
    bc = c;
  }
  // lexicographic (d, c) min across the wave
#pragma unroll
  for (int mm = 1; mm < 64; mm <<= 1) {
    const float od = __shfl_xor(bd, mm, 64);
    const int oc = __shfl_xor(bc, mm, 64);
    if (od < bd || (od == bd && oc < bc)) { bd = od; bc = oc; }
  }
  if (lane == 0) idxout[row] = (float)bc;
}

// ---------------- 4) gather + straight-through output + loss ---------------
// Grid-stride over 4,194,304 float4-chunks with 1024 blocks: ONE fp64 atomic
// per block.
__global__ __launch_bounds__(256) void writeout_k(
    const float* __restrict__ z, const float* __restrict__ e,
    const float* __restrict__ idxf, float* __restrict__ outq,
    double* __restrict__ accum)
{
  const int tid = threadIdx.x;
  double s = 0.0;
  size_t gid = (size_t)blockIdx.x * 256 + tid;
#pragma unroll 1
  for (int it = 0; it < 16; ++it, gid += 262144) {
    const int row = (int)(gid >> 7);
    const int dq = ((int)gid & 127) << 2;
    const int c = (int)idxf[row];
    const float4 q4 = *(const float4*)(e + (size_t)c * DIM + dq);
    const float4 z4 = *(const float4*)(z + (size_t)row * DIM + dq);
    const float tx = q4.x - z4.x, ty = q4.y - z4.y, tz = q4.z - z4.z, tw = q4.w - z4.w;
    float4 o;
    o.x = z4.x + tx; o.y = z4.y + ty; o.z = z4.z + tz; o.w = z4.w + tw;
    *(float4*)(outq + (size_t)row * DIM + dq) = o;
    s += (double)tx * tx + (double)ty * ty + (double)tz * tz + (double)tw * tw;
  }
#pragma unroll
  for (int m = 1; m < 64; m <<= 1) s += shfl_xor_dbl(s, m);
  __shared__ double wsum[4];
  if ((tid & 63) == 0) wsum[tid >> 6] = s;
  __syncthreads();
  if (tid == 0) atomicAdd(accum, wsum[0] + wsum[1] + wsum[2] + wsum[3]);
}

// ---------------- 5) finalize loss -----------------------------------------
__global__ void finalize_k(const double* __restrict__ accum, float* __restrict__ lossp) {
  *lossp = (float)(1.25 * accum[0] / (double)((size_t)N_ROWS * DIM));
}

// ---------------------------------------------------------------------------
extern "C" void kernel_launch(void* const* d_in, const int* in_sizes, int n_in,
                              void* d_out, int out_size, void* d_ws, size_t ws_size,
                              hipStream_t stream) {
  const float* z = (const float*)d_in[0];   // [32768*512] f32
  const float* e = (const float*)d_in[1];   // [8192*512]  f32
  float* out = (float*)d_out;
  char* ob = (char*)d_out;

  // scratch inside the 64MB quantized region (overwritten by writeout_k)
  unsigned short* zb = (unsigned short*)ob;                  // 33,554,432 B
  unsigned short* eb = (unsigned short*)(ob + 33554432);     //  8,388,608 B
  float* b32   = (float*)(ob + 41943040);                    //     32,768 B
  float* a32   = (float*)(ob + 41975808);                    //    131,072 B
  float* candk = (float*)(ob + 42106880);                    //  8,388,608 B
  int*   candi = (int*)(ob + 50495488);                      //  8,388,608 B

  float* lossp = out + 16777216;
  float* idxs  = out + 16777217;
  double* accum = (double*)d_ws;

  hipMemsetAsync(d_ws, 0, sizeof(double), stream);
  cvtnorm_k<<<10240, 256, 0, stream>>>(z, e, zb, eb, a32, b32);
  gemm_topk<<<1024, 512, 0, stream>>>(zb, eb, b32, candk, candi);
  rescore_np<<<8192, 256, 0, stream>>>(z, e, a32, b32, candk, candi, idxs);
  writeout_k<<<1024, 256, 0, stream>>>(z, e, idxs, out, accum);
  finalize_k<<<1, 1, 0, stream>>>(accum, lossp);
}

// Round 10
// 770.012 us; speedup vs baseline: 1.0914x; 1.0193x over previous
//
#include <hip/hip_runtime.h>

// ---------------------------------------------------------------------------
// VectorQuantizer, np-fp32-faithful argmin. Round 15 = r14 + A-traffic tile:
//   THEORY: FETCH 1.066GB = 264MB XCD-compulsory + ~0.8GB A re-staging
//   (256KB A-slice re-staged every ct, 8x/block, ~50% L2 miss). Geometry
//   fix: 128 rows x (4ct x 256 codes) instead of 256 x (8ct x 128):
//   A-slice 128KB re-staged 4x -> A pre-L2 traffic 2GB -> 1GB; kt-barriers
//   128 -> 64. Same 24KB buffer (A 8K + B 16K), same 3 loads/thread, same
//   counted-vmcnt(3) triple-buffer pipeline, same LDS total, same VGPRs.
//   Waves 2x4 (wm row-half, wn code-quarter), wave tile 64x64 unchanged.
//   Scan: scorebuf [128][132] (q-block stride 33: read banks srow*4+q+cc ->
//   2-way free), per-thread top-4 persists over (ct,h) = 256-code subsets,
//   final lane-pair lex merge (r11-verified pattern) -> top-4 per 512-code
//   subset; candk/candi layout unchanged -> rescore/writeout untouched.
//   A/B LEDGER: r10 gemm 423/418 best; NT ✗; setprio ✗; reg-scan ✗ (spill);
//   M256 tile ✓ (FETCH 2.08->1.07GB); counted-vmcnt pipe ✓ (583->423).
// Scratch inside d_out quantized region (overwritten by writeout_k):
//   [0) zb 32MB][32M) eb 8MB][40M) b32 32KB][+32K) a32 128KB]
//   [+128K) candk 8MB][+8M) candi 8MB]   (ends ~58.9MB < 64MB)
// d_ws: 8 bytes (loss accumulator).
// ---------------------------------------------------------------------------

#define N_ROWS 32768
#define K_CODES 8192
#define DIM 512

typedef __attribute__((ext_vector_type(8))) short short8;
typedef __attribute__((ext_vector_type(4))) float f32x4;

#define MARGIN 5e-4f

__device__ __forceinline__ unsigned short f2bf(float f) {
  unsigned int u = __float_as_uint(f);
  u = u + 0x7fffu + ((u >> 16) & 1u);   // round-to-nearest-even
  return (unsigned short)(u >> 16);
}

__device__ __forceinline__ double shfl_xor_dbl(double v, int m) {
  union { double d; int i[2]; } u;
  u.d = v;
  u.i[0] = __shfl_xor(u.i[0], m, 64);
  u.i[1] = __shfl_xor(u.i[1], m, 64);
  return u.d;
}

// opaque: block fp contraction across this value (keep separate RN32 steps)
__device__ __forceinline__ float opaque_f(float x) {
  asm volatile("" : "+v"(x));
  return x;
}

// --- 1) fused fp32 -> bf16 + row squared-norm, z AND e in one launch -------
__global__ __launch_bounds__(256) void cvtnorm_k(
    const float* __restrict__ z, const float* __restrict__ e,
    unsigned short* __restrict__ zb, unsigned short* __restrict__ eb,
    float* __restrict__ a32, float* __restrict__ b32) {
  const int r = blockIdx.x * 4 + (threadIdx.x >> 6);
  const int lane = threadIdx.x & 63;
  const float* in; unsigned short* outb; float* outn; int rr;
  if (r < N_ROWS) { in = z; outb = zb; outn = a32; rr = r; }
  else            { in = e; outb = eb; outn = b32; rr = r - N_ROWS; }
  const float* xr = in + (size_t)rr * DIM + lane * 8;
  const float4 a = *(const float4*)xr;
  const float4 b = *(const float4*)(xr + 4);
  uint4 o;
  o.x = (unsigned)f2bf(a.x) | ((unsigned)f2bf(a.y) << 16);
  o.y = (unsigned)f2bf(a.z) | ((unsigned)f2bf(a.w) << 16);
  o.z = (unsigned)f2bf(b.x) | ((unsigned)f2bf(b.y) << 16);
  o.w = (unsigned)f2bf(b.z) | ((unsigned)f2bf(b.w) << 16);
  *(uint4*)(outb + (size_t)rr * DIM + lane * 8) = o;
  double s = (double)a.x * a.x + (double)a.y * a.y + (double)a.z * a.z + (double)a.w * a.w
           + (double)b.x * b.x + (double)b.y * b.y + (double)b.z * b.z + (double)b.w * b.w;
#pragma unroll
  for (int m = 1; m < 64; m <<= 1) s += shfl_xor_dbl(s, m);
  if (lane == 0) outn[rr] = (float)s;
}

// ---------------- 2) bf16 GEMM + fused streamed top-4 ----------------------
// grid 2048: bx=blk>>3 -> 128 z-rows; by=blk&7 -> 1024-code chunk (4ct x 256).
// Block 512 = 8 waves 2x4 (wm row-half, wn code-quarter); wave tile 64x64 =
// 4x4 MFMA 16x16x32; BK=32, 16 kt per ct.
// Triple-buffered staging (24KB = A 8K + B 16K): 0 / 24576 / 49152.
// scorebuf [128][132] f32 = 67584B aliases staging (post-drain only);
// e2sAll [1024] f32 at 73728. LDS 77824 -> 2 blocks/CU.
// Swizzle: row r (64B) slot s holds source chunk s ^ ((r>>1)&3).
__global__ __launch_bounds__(512, 4) void gemm_topk(
    const unsigned short* __restrict__ A,   // z bf16 [32768][512]
    const unsigned short* __restrict__ B,   // e bf16 [8192][512]
    const float* __restrict__ en2,          // [8192] = b32
    float* __restrict__ candk,              // [32768][64]
    int* __restrict__ candi)                // [32768][64]
{
  __shared__ char lds[77824];
  float* scorebuf = (float*)lds;                 // [128][132], aliases staging
  float* e2sAll = (float*)(lds + 73728);         // [1024]

  const int tid = threadIdx.x;
  const int lane = tid & 63, wave = tid >> 6;    // wave 0..7
  const int wm = wave >> 2, wn = wave & 3;       // 2x4 wave grid
  const int quad = lane >> 4, lcol = lane & 15;
  const int bx = blockIdx.x >> 3, by = blockIdx.x & 7;
  const int row0 = bx * 128;
  const int cstart = by * 1024;                  // 4 ct x 256 codes
  const int srow = tid >> 2, q = tid & 3;        // scan ownership: row x 32-code

  // preload all 1024 e-norms for this chunk (keeps VMEM out of vmcnt count)
  e2sAll[tid] = en2[cstart + tid];
  e2sAll[tid + 512] = en2[cstart + 512 + tid];

  float tk0 = 3.4e38f, tk1 = 3.4e38f, tk2 = 3.4e38f, tk3 = 3.4e38f;
  int ti0 = 0, ti1 = 0, ti2 = 0, ti3 = 0;

  // staging: lane l covers (row = base + (l>>2), lds-slot = l&3); source
  // chunk pre-permuted: sch = (l&3) ^ ((l>>3)&3)  [= slot ^ ((row>>1)&3),
  // valid since all row-bases are multiples of 8]
  const int schm = (lane & 3) ^ ((lane >> 3) & 3);
  const unsigned short* Ag =
      A + ((size_t)(row0 + wave * 16 + (lane >> 2))) * DIM + schm * 8;
  const int dstA = wave * 1024;                  // A [0,8K): 16 rows/wave
  const int dstB = 8192 + wave * 2048;           // B [8K,24K): 32 rows/wave

  // fragment readers: row byte base + swizzled chunk offset
  const int swz = (quad ^ ((lcol >> 1) & 3)) * 16;
  int aoff[4], boff[4];
#pragma unroll
  for (int i = 0; i < 4; ++i) aoff[i] = (wm * 64 + i * 16 + lcol) * 64 + swz;
#pragma unroll
  for (int j = 0; j < 4; ++j) boff[j] = 8192 + (wn * 64 + j * 16 + lcol) * 64 + swz;

#define ASGP const __attribute__((address_space(1))) void*
#define LDSP __attribute__((address_space(3))) void*
#define STAGE(ktv, bb) do {                                                        \
    const unsigned short* As_ = Ag + (ktv) * 32;                                   \
    const unsigned short* Bs_ = Bg + (ktv) * 32;                                   \
    __builtin_amdgcn_global_load_lds((ASGP)(uintptr_t)(As_),                       \
        (LDSP)(uintptr_t)(lds + (bb) + dstA), 16, 0, 0);                           \
    __builtin_amdgcn_global_load_lds((ASGP)(uintptr_t)(Bs_),                       \
        (LDSP)(uintptr_t)(lds + (bb) + dstB), 16, 0, 0);                           \
    __builtin_amdgcn_global_load_lds((ASGP)(uintptr_t)(Bs_ + 16 * DIM),            \
        (LDSP)(uintptr_t)(lds + (bb) + dstB + 1024), 16, 0, 0);                    \
  } while (0)

#define COMPUTE(cbb) do {                                                          \
    short8 af[4], bv[4];                                                           \
    _Pragma("unroll")                                                              \
    for (int i = 0; i < 4; ++i) af[i] = *(const short8*)(lds + (cbb) + aoff[i]);   \
    _Pragma("unroll")                                                              \
    for (int j = 0; j < 4; ++j) bv[j] = *(const short8*)(lds + (cbb) + boff[j]);   \
    _Pragma("unroll")                                                              \
    for (int i = 0; i < 4; ++i)                                                    \
      _Pragma("unroll")                                                            \
      for (int j = 0; j < 4; ++j)                                                  \
        acc[i][j] = __builtin_amdgcn_mfma_f32_16x16x32_bf16(af[i], bv[j],          \
                                                            acc[i][j], 0, 0, 0);   \
  } while (0)

// top-4 insert: strict key-<; ascending-id traversal keeps earliest id
#define INS(sv, idv) do { \
    if ((sv) < tk3) { \
      const int id_ = (idv); \
      if ((sv) < tk2) { \
        tk3 = tk2; ti3 = ti2; \
        if ((sv) < tk1) { \
          tk2 = tk1; ti2 = ti1; \
          if ((sv) < tk0) { tk1 = tk0; ti1 = ti0; tk0 = (sv); ti0 = id_; } \
          else            { tk1 = (sv); ti1 = id_; } \
        } else { tk2 = (sv); ti2 = id_; } \
      } else { tk3 = (sv); ti3 = id_; } \
    } \
  } while (0)

// merge insert: full lexicographic (key,id) -> symmetric deterministic merge
#define LTL(sv, idv, K, I) ((sv) < (K) || ((sv) == (K) && (idv) < (I)))
#define INSM(sv, idv) do { \
    if (LTL(sv, idv, tk3, ti3)) { \
      if (LTL(sv, idv, tk2, ti2)) { tk3 = tk2; ti3 = ti2; \
        if (LTL(sv, idv, tk1, ti1)) { tk2 = tk1; ti2 = ti1; \
          if (LTL(sv, idv, tk0, ti0)) { tk1 = tk0; ti1 = ti0; tk0 = (sv); ti0 = (idv); } \
          else { tk1 = (sv); ti1 = (idv); } \
        } else { tk2 = (sv); ti2 = (idv); } \
      } else { tk3 = (sv); ti3 = (idv); } \
    } \
  } while (0)

#pragma unroll 1
  for (int ct = 0; ct < 4; ++ct) {
    const int c0 = cstart + ct * 256;
    const unsigned short* Bg =
        B + ((size_t)(c0 + wave * 32 + (lane >> 2))) * DIM + schm * 8;

    f32x4 acc[4][4];
#pragma unroll
    for (int i = 0; i < 4; ++i)
#pragma unroll
      for (int j = 0; j < 4; ++j) acc[i][j] = 0.f;

    __syncthreads();                 // staging/scorebuf region free (drains all)
    STAGE(0, 0);
    STAGE(1, 24576);
    int cb = 0, nb = 24576, fb = 49152;   // rotating buffer bases
#pragma unroll 1
    for (int kt = 0; kt < 15; ++kt) {
      // own STAGE(kt) landed (in-order retirement; kt+1 may stay in flight)
      asm volatile("s_waitcnt vmcnt(3)" ::: "memory");
      __builtin_amdgcn_s_barrier();          // => ALL waves' STAGE(kt) landed
      asm volatile("" ::: "memory");         // no memory op hoists above barrier
      __builtin_amdgcn_sched_barrier(0);
      // fb == buffer read at COMPUTE(kt-1); its readers retired their ds_reads
      // before the barrier above -> safe to overwrite now.
      if (kt < 14) STAGE(kt + 2, fb);
      COMPUTE(cb);
      const int t = cb; cb = nb; nb = fb; fb = t;
    }
    asm volatile("s_waitcnt vmcnt(0)" ::: "memory");
    __builtin_amdgcn_s_barrier();
    asm volatile("" ::: "memory");
    __builtin_amdgcn_sched_barrier(0);
    COMPUTE(cb);                     // kt=15 (15%3==0 -> cb cycled back to 0)

    // epilogue: 2 h-phases of 128 codes; scorebuf row stride 132, q-block
    // stride 33 (scan banks = srow*4+q+cc -> exact 2-way, free)
#pragma unroll 1
    for (int h = 0; h < 2; ++h) {
      __syncthreads();
      if ((wn >> 1) == h) {
#pragma unroll
        for (int i = 0; i < 4; ++i)
#pragma unroll
          for (int j = 0; j < 4; ++j) {
            const int colb = (wn & 1) * 64 + j * 16;      // 0,16,..,112
            const float eb2 = e2sAll[ct * 256 + h * 128 + colb + lcol];
            const int cidx = ((colb + lcol) >> 5) * 33 + ((colb & 31)) + lcol;
#pragma unroll
            for (int r = 0; r < 4; ++r)
              scorebuf[(wm * 64 + i * 16 + quad * 4 + r) * 132 + cidx] =
                  fmaf(acc[i][j][r], -2.0f, eb2);
          }
      }
      __syncthreads();
      const float* sp = scorebuf + srow * 132 + q * 33;
      const int idbase = c0 + h * 128 + q * 32;
#pragma unroll 8
      for (int cc = 0; cc < 32; ++cc) {
        const float key = sp[cc];
        if (key < tk3) INS(key, idbase + cc);
      }
    }
  }

  // merge q-pairs (lane xor 1): lex (key,id) snapshot-insert -> both lanes of
  // the pair end with identical top-4 of their 512-code subset union.
  {
    float ok0 = __shfl_xor(tk0, 1, 64), ok1 = __shfl_xor(tk1, 1, 64);
    float ok2 = __shfl_xor(tk2, 1, 64), ok3 = __shfl_xor(tk3, 1, 64);
    int oi0 = __shfl_xor(ti0, 1, 64), oi1 = __shfl_xor(ti1, 1, 64);
    int oi2 = __shfl_xor(ti2, 1, 64), oi3 = __shfl_xor(ti3, 1, 64);
    INSM(ok0, oi0); INSM(ok1, oi1); INSM(ok2, oi2); INSM(ok3, oi3);
  }
  if ((q & 1) == 0) {
    const size_t cb2 = ((size_t)(row0 + srow)) * 64 + by * 8 + (q >> 1) * 4;
    float4 kf; kf.x = tk0; kf.y = tk1; kf.z = tk2; kf.w = tk3;
    int4 fi; fi.x = ti0; fi.y = ti1; fi.z = ti2; fi.w = ti3;
    *(float4*)(candk + cb2) = kf;
    *(int4*)(candi + cb2) = fi;
  }
}

// ---------------- 3) np-faithful fp32 rescore, wave-per-row ----------------
// One wave per row; LANE j owns candidate j (64 in parallel). Per-candidate
// arithmetic bit-identical: OpenBLAS sgemm model m32 = RN32(chain(0..383) +
// chain(384..511)), sequential fp32 fma chains; d = RN32(RN32(a+b)-RN32(2m)).
// Winner = lexicographic min (d, c).
__global__ __launch_bounds__(256) void rescore_np(
    const float* __restrict__ z, const float* __restrict__ e,
    const float* __restrict__ a32, const float* __restrict__ b32,
    const float* __restrict__ candk, const int* __restrict__ candi,
    float* __restrict__ idxout)
{
  const int row = blockIdx.x * 4 + (threadIdx.x >> 6);
  const int lane = threadIdx.x & 63;

  const float myk = candk[(size_t)row * 64 + lane];
  float kmin = myk;
#pragma unroll
  for (int m = 1; m < 64; m <<= 1) kmin = fminf(kmin, __shfl_xor(kmin, m, 64));
  const float cut = kmin + MARGIN;

  float bd = 3.4e38f;
  int bc = 0x7fffffff;
  if (myk <= cut) {
    const int c = candi[(size_t)row * 64 + lane];
    const float* zr = z + (size_t)row * DIM;
    const float* er = e + (size_t)c * DIM;
    // panel A: k = 0..383, sequential fp32 fma chain
    float s = 0.0f;
#pragma unroll 4
    for (int k4 = 0; k4 < 96; ++k4) {
      const float4 zv = *(const float4*)(zr + k4 * 4);
      const float4 ev = *(const float4*)(er + k4 * 4);
      s = fmaf(zv.x, ev.x, s);
      s = fmaf(zv.y, ev.y, s);
      s = fmaf(zv.z, ev.z, s);
      s = fmaf(zv.w, ev.w, s);
    }
    const float cA = s;
    // panel B: k = 384..511
    s = 0.0f;
#pragma unroll 4
    for (int k4 = 96; k4 < 128; ++k4) {
      const float4 zv = *(const float4*)(zr + k4 * 4);
      const float4 ev = *(const float4*)(er + k4 * 4);
      s = fmaf(zv.x, ev.x, s);
      s = fmaf(zv.y, ev.y, s);
      s = fmaf(zv.z, ev.z, s);
      s = fmaf(zv.w, ev.w, s);
    }
    const float m = cA + s;                    // RN32 panel combine
    const float t1 = a32[row] + b32[c];        // RN32(a + b_c)
    const float t2 = opaque_f(2.0f * m);       // RN32(2*m), no contraction
    bd = t1 - t2;                              // RN32(t1 - t2)
    bc = c;
  }
  // lexicographic (d, c) min across the wave
#pragma unroll
  for (int mm = 1; mm < 64; mm <<= 1) {
    const float od = __shfl_xor(bd, mm, 64);
    const int oc = __shfl_xor(bc, mm, 64);
    if (od < bd || (od == bd && oc < bc)) { bd = od; bc = oc; }
  }
  if (lane == 0) idxout[row] = (float)bc;
}

// ---------------- 4) gather + straight-through output + loss ---------------
// Grid-stride over 4,194,304 float4-chunks with 1024 blocks: ONE fp64 atomic
// per block.
__global__ __launch_bounds__(256) void writeout_k(
    const float* __restrict__ z, const float* __restrict__ e,
    const float* __restrict__ idxf, float* __restrict__ outq,
    double* __restrict__ accum)
{
  const int tid = threadIdx.x;
  double s = 0.0;
  size_t gid = (size_t)blockIdx.x * 256 + tid;
#pragma unroll 1
  for (int it = 0; it < 16; ++it, gid += 262144) {
    const int row = (int)(gid >> 7);
    const int dq = ((int)gid & 127) << 2;
    const int c = (int)idxf[row];
    const float4 q4 = *(const float4*)(e + (size_t)c * DIM + dq);
    const float4 z4 = *(const float4*)(z + (size_t)row * DIM + dq);
    const float tx = q4.x - z4.x, ty = q4.y - z4.y, tz = q4.z - z4.z, tw = q4.w - z4.w;
    float4 o;
    o.x = z4.x + tx; o.y = z4.y + ty; o.z = z4.z + tz; o.w = z4.w + tw;
    *(float4*)(outq + (size_t)row * DIM + dq) = o;
    s += (double)tx * tx + (double)ty * ty + (double)tz * tz + (double)tw * tw;
  }
#pragma unroll
  for (int m = 1; m < 64; m <<= 1) s += shfl_xor_dbl(s, m);
  __shared__ double wsum[4];
  if ((tid & 63) == 0) wsum[tid >> 6] = s;
  __syncthreads();
  if (tid == 0) atomicAdd(accum, wsum[0] + wsum[1] + wsum[2] + wsum[3]);
}

// ---------------- 5) finalize loss -----------------------------------------
__global__ void finalize_k(const double* __restrict__ accum, float* __restrict__ lossp) {
  *lossp = (float)(1.25 * accum[0] / (double)((size_t)N_ROWS * DIM));
}

// ---------------------------------------------------------------------------
extern "C" void kernel_launch(void* const* d_in, const int* in_sizes, int n_in,
                              void* d_out, int out_size, void* d_ws, size_t ws_size,
                              hipStream_t stream) {
  const float* z = (const float*)d_in[0];   // [32768*512] f32
  const float* e = (const float*)d_in[1];   // [8192*512]  f32
  float* out = (float*)d_out;
  char* ob = (char*)d_out;

  // scratch inside the 64MB quantized region (overwritten by writeout_k)
  unsigned short* zb = (unsigned short*)ob;                  // 33,554,432 B
  unsigned short* eb = (unsigned short*)(ob + 33554432);     //  8,388,608 B
  float* b32   = (float*)(ob + 41943040);                    //     32,768 B
  float* a32   = (float*)(ob + 41975808);                    //    131,072 B
  float* candk = (float*)(ob + 42106880);                    //  8,388,608 B
  int*   candi = (int*)(ob + 50495488);                      //  8,388,608 B

  float* lossp = out + 16777216;
  float* idxs  = out + 16777217;
  double* accum = (double*)d_ws;

  hipMemsetAsync(d_ws, 0, sizeof(double), stream);
  cvtnorm_k<<<10240, 256, 0, stream>>>(z, e, zb, eb, a32, b32);
  gemm_topk<<<2048, 512, 0, stream>>>(zb, eb, b32, candk, candi);
  rescore_np<<<8192, 256, 0, stream>>>(z, e, a32, b32, candk, candi, idxs);
  writeout_k<<<1024, 256, 0, stream>>>(z, e, idxs, out, accum);
  finalize_k<<<1, 1, 0, stream>>>(accum, lossp);
}